// Round 1
// baseline (841.885 us; speedup 1.0000x reference)
//
#include <hip/hip_runtime.h>
#include <math.h>

typedef __attribute__((ext_vector_type(4))) int   i32x4;
typedef __attribute__((ext_vector_type(4))) float f32x4;

#define NTOK   8192
#define DIMD   1024
#define HID    2048
#define NEXP   8
#define NPAIR  16384

// ---- workspace byte offsets ----
#define XQ_OFF      0L           // int8 [8192][1024]
#define WQIN_OFF    8388608L     // int8 [8][4096][1024]
#define WQOUT_OFF   41943040L    // int8 [8][1024][2048]
#define HQ_OFF      58720256L    // int8 [16384][2048]
#define GLU_OFF     92274688L    // f32  [16384][2048]
#define XREC_OFF    226492416L   // f32 [8192]
#define GATE_OFF    226525184L   // f32 [16384]
#define HREC_OFF    226590720L   // f32 [16384]
#define HABS_OFF    226656256L   // u32 [16384]
#define TLIST_OFF   226721792L   // int [8][8192]
#define CNT_OFF     226983936L   // int [8]
#define PSUM_OFF    226983968L   // f32 [8]
#define ZSUM_OFF    226984000L   // f32 [1]
#define PART_OFF    226984032L   // f32 [768]
#define WRECIN_OFF  226988128L
#define WRECOUT_OFF 226988160L
#define WSCLIN_OFF  226988192L
#define WSCLOUT_OFF 226988224L

__device__ __forceinline__ int clampi(int v, int lo, int hi){ return v<lo?lo:(v>hi?hi:v); }

__device__ __forceinline__ unsigned packq(f32x4 v, float s, int lo, int hi){
  int q0 = clampi((int)rintf(v.x*s), lo, hi);
  int q1 = clampi((int)rintf(v.y*s), lo, hi);
  int q2 = clampi((int)rintf(v.z*s), lo, hi);
  int q3 = clampi((int)rintf(v.w*s), lo, hi);
  return (unsigned)((q0&255)|((q1&255)<<8)|((q2&255)<<16)|((q3&255)<<24));
}

// ---------------- init: y <- bias, zero accumulators ----------------
__global__ void k_init(float* __restrict__ y, const float* __restrict__ bias,
                       unsigned* __restrict__ habs, int* __restrict__ cnts,
                       float* __restrict__ psum, float* __restrict__ zsum){
  long i = (long)blockIdx.x*blockDim.x + threadIdx.x;
  long st = (long)gridDim.x*blockDim.x;
  for (long j=i; j<(long)NTOK*DIMD; j+=st) y[j] = bias[j & (DIMD-1)];
  for (long j=i; j<NPAIR; j+=st) habs[j] = 0u;
  if (i<8){ cnts[i]=0; psum[i]=0.f; }
  if (i==8) zsum[0]=0.f;
}

// ---------------- router + act_quant(x) ----------------
// one wave per token; block = 1024 threads = 16 tokens
__global__ __launch_bounds__(1024) void k_router(
    const float* __restrict__ x, const float* __restrict__ wg,
    signed char* __restrict__ xq, float* __restrict__ xrec,
    float* __restrict__ gatep, int* __restrict__ tlist, int* __restrict__ cnts,
    float* __restrict__ psum, float* __restrict__ zsum)
{
  __shared__ float ls_p[8]; __shared__ float ls_z[1];
  __shared__ int ls_c[8];  __shared__ int ls_b[8];
  int tid = threadIdx.x;
  if (tid<8){ ls_p[tid]=0.f; ls_c[tid]=0; }
  if (tid==8) ls_z[0]=0.f;
  __syncthreads();
  int wave = tid>>6, lane = tid&63;
  int tok = blockIdx.x*16 + wave;

  const f32x4* x4 = (const f32x4*)(x + (long)tok*DIMD) + lane*4;
  f32x4 xv[4];
  #pragma unroll
  for (int j=0;j<4;++j) xv[j] = x4[j];

  float amax = 0.f;
  float lg[8] = {0,0,0,0,0,0,0,0};
  const f32x4* wg4 = (const f32x4*)wg;
  #pragma unroll
  for (int j=0;j<16;++j){
    float xd = xv[j>>2][j&3];
    amax = fmaxf(amax, fabsf(xd));
    int d = lane*16 + j;
    f32x4 w0 = wg4[d*2], w1 = wg4[d*2+1];
    lg[0]+=xd*w0.x; lg[1]+=xd*w0.y; lg[2]+=xd*w0.z; lg[3]+=xd*w0.w;
    lg[4]+=xd*w1.x; lg[5]+=xd*w1.y; lg[6]+=xd*w1.z; lg[7]+=xd*w1.w;
  }
  for (int m=1;m<64;m<<=1){
    amax = fmaxf(amax, __shfl_xor(amax, m));
    #pragma unroll
    for (int e=0;e<8;++e) lg[e] += __shfl_xor(lg[e], m);
  }
  float cm = fmaxf(amax, 1e-5f);
  float sx = 127.f/cm;
  unsigned p0 = packq(xv[0], sx, -128, 127);
  unsigned p1 = packq(xv[1], sx, -128, 127);
  unsigned p2 = packq(xv[2], sx, -128, 127);
  unsigned p3 = packq(xv[3], sx, -128, 127);
  i32x4 pk; pk.x=(int)p0; pk.y=(int)p1; pk.z=(int)p2; pk.w=(int)p3;
  *(i32x4*)(xq + (long)tok*DIMD + lane*16) = pk;

  int e1=0, e2=0, s1=0, s2=0;
  if (lane==0){
    xrec[tok] = cm*(1.f/127.f);
    e1 = 0;
    for (int e=1;e<8;++e) if (lg[e] > lg[e1]) e1 = e;
    e2 = (e1==0)?1:0;
    for (int e=0;e<8;++e) if (e!=e1 && lg[e] > lg[e2]) e2 = e;
    float t = expf(lg[e2]-lg[e1]);
    gatep[tok*2]   = 1.f/(1.f+t);
    gatep[tok*2+1] = t/(1.f+t);
    float mx = lg[e1], sum = 0.f, pr[8];
    #pragma unroll
    for (int e=0;e<8;++e){ pr[e] = expf(lg[e]-mx); sum += pr[e]; }
    float inv = 1.f/sum;
    #pragma unroll
    for (int e=0;e<8;++e) atomicAdd(&ls_p[e], pr[e]*inv);
    float lse = mx + logf(sum);
    atomicAdd(&ls_z[0], lse*lse);
    s1 = atomicAdd(&ls_c[e1], 1);
    s2 = atomicAdd(&ls_c[e2], 1);
  }
  __syncthreads();
  if (tid<8) ls_b[tid] = atomicAdd(&cnts[tid], ls_c[tid]);
  __syncthreads();
  if (lane==0){
    tlist[e1*NTOK + ls_b[e1] + s1] = tok*2;
    tlist[e2*NTOK + ls_b[e2] + s2] = tok*2 + 1;
  }
  if (tid<8)  atomicAdd(&psum[tid], ls_p[tid]);
  if (tid==8) atomicAdd(zsum, ls_z[0]);
}

// ---------------- weight |w| partial sums ----------------
__global__ void k_wabs(const float* __restrict__ w_in, const float* __restrict__ w_out,
                       float* __restrict__ part){
  int b = blockIdx.x, tid = threadIdx.x;
  const float* base = (b < 512) ? (w_in + (long)b*65536) : (w_out + (long)(b-512)*65536);
  const f32x4* p4 = (const f32x4*)base;
  float s = 0.f;
  for (int i = tid; i < 16384; i += 256){
    f32x4 v = p4[i];
    s += fabsf(v.x)+fabsf(v.y)+fabsf(v.z)+fabsf(v.w);
  }
  __shared__ float red[256];
  red[tid] = s; __syncthreads();
  for (int off=128; off; off>>=1){ if (tid<off) red[tid]+=red[tid+off]; __syncthreads(); }
  if (tid==0) part[b] = red[0];
}

__global__ void k_wmean(const float* __restrict__ part,
                        float* __restrict__ wrec_in, float* __restrict__ wrec_out,
                        float* __restrict__ wscl_in, float* __restrict__ wscl_out){
  int t = threadIdx.x;
  if (t < 8){
    float s = 0.f;
    for (int i=0;i<64;++i) s += part[t*64+i];
    float cmm = fmaxf(s/4194304.f, 1e-5f);
    wrec_in[t] = cmm; wscl_in[t] = 1.f/cmm;
  } else if (t < 16){
    int e = t-8; float s = 0.f;
    for (int i=0;i<32;++i) s += part[512 + e*32 + i];
    float cmm = fmaxf(s/2097152.f, 1e-5f);
    wrec_out[e] = cmm; wscl_out[e] = 1.f/cmm;
  }
}

// ---------------- ternarize weights -> int8 ----------------
__global__ void k_quantw(const float* __restrict__ w, unsigned* __restrict__ wq,
                         const float* __restrict__ wscl, int lg2pe, long n4){
  long i = (long)blockIdx.x*blockDim.x + threadIdx.x;
  long st = (long)gridDim.x*blockDim.x;
  for (; i < n4; i += st){
    f32x4 v = ((const f32x4*)w)[i];
    int e = (int)((i<<2) >> lg2pe);
    float s = wscl[e];
    wq[i] = packq(v, s, -1, 1);
  }
}

// ---------------- GEMM1: h = xq @ win^T, fused GLU, write glu + row absmax ----------------
__global__ __launch_bounds__(256) void k_gemm1(
    const signed char* __restrict__ xq, const signed char* __restrict__ wqin,
    const int* __restrict__ tlist, const int* __restrict__ cnts,
    const float* __restrict__ xrec, const float* __restrict__ wrec_in,
    float* __restrict__ glu, unsigned* __restrict__ habs)
{
  const int e = blockIdx.y;
  const int cnt = cnts[e];
  const int slot = blockIdx.x >> 5;
  const int row0 = slot << 7;
  if (row0 >= cnt) return;
  const int ctile = blockIdx.x & 31;              // glu cols [ctile*64, +64)
  const int wave = threadIdx.x >> 6, lane = threadIdx.x & 63;
  const int l15 = lane & 15, lhi = lane >> 4;
  const int rbase = row0 + wave*32;
  const int* tl = tlist + e*NTOK;

  const signed char* aptr[2];
  #pragma unroll
  for (int rt=0; rt<2; ++rt){
    int r = rbase + rt*16 + l15;
    int pr = tl[min(r, cnt-1)];
    aptr[rt] = xq + (long)(pr>>1)*DIMD + lhi*16;
  }
  const signed char* wbase = wqin + (long)e*4194304 + lhi*16;
  const signed char* bptr[8];
  #pragma unroll
  for (int c=0;c<8;++c){
    int wcol = (c<4) ? (ctile*64 + c*16 + l15) : (HID + ctile*64 + (c-4)*16 + l15);
    bptr[c] = wbase + (long)wcol*DIMD;
  }
  i32x4 acc[2][8] = {};
  for (int k=0;k<DIMD;k+=64){
    i32x4 a0 = *(const i32x4*)(aptr[0]+k);
    i32x4 a1 = *(const i32x4*)(aptr[1]+k);
    #pragma unroll
    for (int c=0;c<8;++c){
      i32x4 b = *(const i32x4*)(bptr[c]+k);
      acc[0][c] = __builtin_amdgcn_mfma_i32_16x16x64_i8(a0, b, acc[0][c], 0,0,0);
      acc[1][c] = __builtin_amdgcn_mfma_i32_16x16x64_i8(a1, b, acc[1][c], 0,0,0);
    }
  }
  const float wr = wrec_in[e];
  #pragma unroll
  for (int rt=0; rt<2; ++rt){
    #pragma unroll
    for (int i=0; i<4; ++i){
      int r = rbase + rt*16 + lhi*4 + i;
      bool valid = (r < cnt);
      int pr = valid ? tl[r] : 0;
      float dq = xrec[pr>>1] * wr;
      float m = 0.f;
      #pragma unroll
      for (int c=0;c<4;++c){
        float h1 = (float)acc[rt][c][i]   * dq;
        float gg = (float)acc[rt][c+4][i] * dq;
        float sil = h1 / (1.f + expf(-h1));
        float v = sil * gg;
        m = fmaxf(m, fabsf(v));
        if (valid) glu[(long)pr*HID + ctile*64 + c*16 + l15] = v;
      }
      #pragma unroll
      for (int mm=1; mm<16; mm<<=1) m = fmaxf(m, __shfl_xor(m, mm));
      if (valid && l15==0) atomicMax(habs + pr, __float_as_uint(m));
    }
  }
}

// ---------------- act_quant(glu) -> hq int8 ----------------
__global__ void k_quanth(const float* __restrict__ glu, const unsigned* __restrict__ habs,
                         signed char* __restrict__ hq, float* __restrict__ hrec){
  int p = blockIdx.x, t = threadIdx.x;
  float am = __uint_as_float(habs[p]);
  float cmm = fmaxf(am, 1e-5f);
  if (t==0) hrec[p] = cmm*(1.f/127.f);
  float s = 127.f/cmm;
  const f32x4* g4 = (const f32x4*)(glu + (long)p*HID);
  f32x4 v0 = g4[t*2], v1 = g4[t*2+1];
  uint2 u; u.x = packq(v0, s, -128, 127); u.y = packq(v1, s, -128, 127);
  ((uint2*)(hq + (long)p*HID))[t] = u;
}

// ---------------- GEMM2: y += gate * (hq @ wout^T) ----------------
__global__ __launch_bounds__(256) void k_gemm2(
    const signed char* __restrict__ hq, const signed char* __restrict__ wqout,
    const int* __restrict__ tlist, const int* __restrict__ cnts,
    const float* __restrict__ hrec, const float* __restrict__ gatep,
    const float* __restrict__ wrec_out, float* __restrict__ y)
{
  const int e = blockIdx.y;
  const int cnt = cnts[e];
  const int slot = blockIdx.x >> 3;
  const int row0 = slot << 7;
  if (row0 >= cnt) return;
  const int ctile = blockIdx.x & 7;
  const int dcol0 = ctile*128;
  const int wave = threadIdx.x >> 6, lane = threadIdx.x & 63;
  const int l15 = lane & 15, lhi = lane >> 4;
  const int rbase = row0 + wave*32;
  const int* tl = tlist + e*NTOK;

  const signed char* aptr[2];
  #pragma unroll
  for (int rt=0; rt<2; ++rt){
    int r = rbase + rt*16 + l15;
    int pr = tl[min(r, cnt-1)];
    aptr[rt] = hq + (long)pr*HID + lhi*16;
  }
  const signed char* bptr[8];
  #pragma unroll
  for (int c=0;c<8;++c){
    int wcol = dcol0 + c*16 + l15;
    bptr[c] = wqout + (long)e*2097152 + (long)wcol*HID + lhi*16;
  }
  i32x4 acc[2][8] = {};
  for (int k=0;k<HID;k+=64){
    i32x4 a0 = *(const i32x4*)(aptr[0]+k);
    i32x4 a1 = *(const i32x4*)(aptr[1]+k);
    #pragma unroll
    for (int c=0;c<8;++c){
      i32x4 b = *(const i32x4*)(bptr[c]+k);
      acc[0][c] = __builtin_amdgcn_mfma_i32_16x16x64_i8(a0, b, acc[0][c], 0,0,0);
      acc[1][c] = __builtin_amdgcn_mfma_i32_16x16x64_i8(a1, b, acc[1][c], 0,0,0);
    }
  }
  const float wr = wrec_out[e];
  #pragma unroll
  for (int rt=0; rt<2; ++rt){
    #pragma unroll
    for (int i=0; i<4; ++i){
      int r = rbase + rt*16 + lhi*4 + i;
      bool valid = (r < cnt);
      int pr = valid ? tl[r] : 0;
      if (!valid) continue;
      int tok = pr >> 1;
      float f = gatep[pr] * hrec[pr] * wr;
      #pragma unroll
      for (int c=0;c<8;++c)
        atomicAdd(y + (long)tok*DIMD + dcol0 + c*16 + l15, (float)acc[rt][c][i] * f);
    }
  }
}

// ---------------- loss ----------------
__global__ void k_loss(const int* __restrict__ cnts, const float* __restrict__ psum,
                       const float* __restrict__ zsum, float* __restrict__ out){
  if (threadIdx.x==0 && blockIdx.x==0){
    float sp=0.f, sf=0.f, sw=0.f;
    for (int e=0;e<8;++e){
      float f = (float)cnts[e];
      sp += psum[e]; sf += f; sw += psum[e]*f;
    }
    float loss = 8.f*sw/(sp*sf) + 0.1f*zsum[0]/(float)NTOK;
    out[(long)NTOK*DIMD] = loss;
  }
}

extern "C" void kernel_launch(void* const* d_in, const int* in_sizes, int n_in,
                              void* d_out, int out_size, void* d_ws, size_t ws_size,
                              hipStream_t stream){
  const float* x     = (const float*)d_in[0];
  const float* wg    = (const float*)d_in[1];
  const float* w_in  = (const float*)d_in[2];
  const float* w_out = (const float*)d_in[3];
  const float* bias  = (const float*)d_in[4];
  float* y = (float*)d_out;
  char* ws = (char*)d_ws;

  signed char* xq    = (signed char*)(ws + XQ_OFF);
  signed char* wqin  = (signed char*)(ws + WQIN_OFF);
  signed char* wqout = (signed char*)(ws + WQOUT_OFF);
  signed char* hq    = (signed char*)(ws + HQ_OFF);
  float* glu   = (float*)(ws + GLU_OFF);
  float* xrec  = (float*)(ws + XREC_OFF);
  float* gatep = (float*)(ws + GATE_OFF);
  float* hrec  = (float*)(ws + HREC_OFF);
  unsigned* habs = (unsigned*)(ws + HABS_OFF);
  int* tlist = (int*)(ws + TLIST_OFF);
  int* cnts  = (int*)(ws + CNT_OFF);
  float* psum = (float*)(ws + PSUM_OFF);
  float* zsum = (float*)(ws + ZSUM_OFF);
  float* part = (float*)(ws + PART_OFF);
  float* wrec_in  = (float*)(ws + WRECIN_OFF);
  float* wrec_out = (float*)(ws + WRECOUT_OFF);
  float* wscl_in  = (float*)(ws + WSCLIN_OFF);
  float* wscl_out = (float*)(ws + WSCLOUT_OFF);

  k_init  <<<2048, 256, 0, stream>>>(y, bias, habs, cnts, psum, zsum);
  k_router<<<512, 1024, 0, stream>>>(x, wg, xq, xrec, gatep, tlist, cnts, psum, zsum);
  k_wabs  <<<768, 256, 0, stream>>>(w_in, w_out, part);
  k_wmean <<<1, 64, 0, stream>>>(part, wrec_in, wrec_out, wscl_in, wscl_out);
  k_quantw<<<1024, 256, 0, stream>>>(w_in,  (unsigned*)wqin,  wscl_in,  22, 8388608L);
  k_quantw<<<1024, 256, 0, stream>>>(w_out, (unsigned*)wqout, wscl_out, 21, 4194304L);
  k_gemm1 <<<dim3(2048, 8), 256, 0, stream>>>(xq, wqin, tlist, cnts, xrec, wrec_in, glu, habs);
  k_quanth<<<NPAIR, 256, 0, stream>>>(glu, habs, hq, hrec);
  k_gemm2 <<<dim3(512, 8), 256, 0, stream>>>(hq, wqout, tlist, cnts, hrec, gatep, wrec_out, y);
  k_loss  <<<1, 64, 0, stream>>>(cnts, psum, zsum, y);
}

// Round 2
// 496.582 us; speedup vs baseline: 1.6954x; 1.6954x over previous
//
#include <hip/hip_runtime.h>
#include <math.h>

typedef __attribute__((ext_vector_type(4))) int   i32x4;
typedef __attribute__((ext_vector_type(4))) float f32x4;

#define NTOK   8192
#define DIMD   1024
#define HID    2048
#define NEXP   8
#define NPAIR  16384

// ---- workspace byte offsets ----
#define XQ_OFF      0L           // int8 [8192][1024]
#define WQIN_OFF    8388608L     // int8 packed frags [8][256 cb][16 kb][64 lane][16]
#define WQOUT_OFF   41943040L    // int8 packed frags [8][64 cb][32 kb][64 lane][16]
#define HQ_OFF      58720256L    // int8 [16384][2048]
#define GLU_OFF     92274688L    // f32  [16384][2048] ; later reused as pout f32 [16384][1024]
#define XREC_OFF    226492416L   // f32 [8192]
#define GATE_OFF    226525184L   // f32 [16384]
#define HREC_OFF    226590720L   // f32 [16384]
#define HABS_OFF    226656256L   // u32 [16384]
#define TLIST_OFF   226721792L   // int [8][8192]
#define CNT_OFF     226983936L   // int [8]
#define PSUM_OFF    226983968L   // f32 [8]
#define ZSUM_OFF    226984000L   // f32 [1]
#define PART_OFF    226984032L   // f32 [768]
#define WRECIN_OFF  226988128L
#define WRECOUT_OFF 226988160L
#define WSCLIN_OFF  226988192L
#define WSCLOUT_OFF 226988224L

__device__ __forceinline__ int clampi(int v, int lo, int hi){ return v<lo?lo:(v>hi?hi:v); }

__device__ __forceinline__ unsigned packq(f32x4 v, float s, int lo, int hi){
  int q0 = clampi((int)rintf(v.x*s), lo, hi);
  int q1 = clampi((int)rintf(v.y*s), lo, hi);
  int q2 = clampi((int)rintf(v.z*s), lo, hi);
  int q3 = clampi((int)rintf(v.w*s), lo, hi);
  return (unsigned)((q0&255)|((q1&255)<<8)|((q2&255)<<16)|((q3&255)<<24));
}

// ---------------- init: zero accumulators ----------------
__global__ void k_init(unsigned* __restrict__ habs, int* __restrict__ cnts,
                       float* __restrict__ psum, float* __restrict__ zsum){
  int i = blockIdx.x*blockDim.x + threadIdx.x;
  if (i < NPAIR) habs[i] = 0u;
  if (i < 8){ cnts[i]=0; psum[i]=0.f; }
  if (i == 8) zsum[0]=0.f;
}

// ---------------- router + act_quant(x) ----------------
// one wave per token; block = 1024 threads = 16 tokens
__global__ __launch_bounds__(1024) void k_router(
    const float* __restrict__ x, const float* __restrict__ wg,
    signed char* __restrict__ xq, float* __restrict__ xrec,
    float* __restrict__ gatep, int* __restrict__ tlist, int* __restrict__ cnts,
    float* __restrict__ psum, float* __restrict__ zsum)
{
  __shared__ float ls_p[8]; __shared__ float ls_z[1];
  __shared__ int ls_c[8];  __shared__ int ls_b[8];
  int tid = threadIdx.x;
  if (tid<8){ ls_p[tid]=0.f; ls_c[tid]=0; }
  if (tid==8) ls_z[0]=0.f;
  __syncthreads();
  int wave = tid>>6, lane = tid&63;
  int tok = blockIdx.x*16 + wave;

  const f32x4* x4 = (const f32x4*)(x + (long)tok*DIMD) + lane*4;
  f32x4 xv[4];
  #pragma unroll
  for (int j=0;j<4;++j) xv[j] = x4[j];

  float amax = 0.f;
  float lg[8] = {0,0,0,0,0,0,0,0};
  const f32x4* wg4 = (const f32x4*)wg;
  #pragma unroll
  for (int j=0;j<16;++j){
    float xd = xv[j>>2][j&3];
    amax = fmaxf(amax, fabsf(xd));
    int d = lane*16 + j;
    f32x4 w0 = wg4[d*2], w1 = wg4[d*2+1];
    lg[0]+=xd*w0.x; lg[1]+=xd*w0.y; lg[2]+=xd*w0.z; lg[3]+=xd*w0.w;
    lg[4]+=xd*w1.x; lg[5]+=xd*w1.y; lg[6]+=xd*w1.z; lg[7]+=xd*w1.w;
  }
  for (int m=1;m<64;m<<=1){
    amax = fmaxf(amax, __shfl_xor(amax, m));
    #pragma unroll
    for (int e=0;e<8;++e) lg[e] += __shfl_xor(lg[e], m);
  }
  float cm = fmaxf(amax, 1e-5f);
  float sx = 127.f/cm;
  unsigned p0 = packq(xv[0], sx, -128, 127);
  unsigned p1 = packq(xv[1], sx, -128, 127);
  unsigned p2 = packq(xv[2], sx, -128, 127);
  unsigned p3 = packq(xv[3], sx, -128, 127);
  i32x4 pk; pk.x=(int)p0; pk.y=(int)p1; pk.z=(int)p2; pk.w=(int)p3;
  *(i32x4*)(xq + (long)tok*DIMD + lane*16) = pk;

  int e1=0, e2=0, s1=0, s2=0;
  if (lane==0){
    xrec[tok] = cm*(1.f/127.f);
    e1 = 0;
    for (int e=1;e<8;++e) if (lg[e] > lg[e1]) e1 = e;
    e2 = (e1==0)?1:0;
    for (int e=0;e<8;++e) if (e!=e1 && lg[e] > lg[e2]) e2 = e;
    float t = expf(lg[e2]-lg[e1]);
    gatep[tok*2]   = 1.f/(1.f+t);
    gatep[tok*2+1] = t/(1.f+t);
    float mx = lg[e1], sum = 0.f, pr[8];
    #pragma unroll
    for (int e=0;e<8;++e){ pr[e] = expf(lg[e]-mx); sum += pr[e]; }
    float inv = 1.f/sum;
    #pragma unroll
    for (int e=0;e<8;++e) atomicAdd(&ls_p[e], pr[e]*inv);
    float lse = mx + logf(sum);
    atomicAdd(&ls_z[0], lse*lse);
    s1 = atomicAdd(&ls_c[e1], 1);
    s2 = atomicAdd(&ls_c[e2], 1);
  }
  __syncthreads();
  if (tid<8) ls_b[tid] = atomicAdd(&cnts[tid], ls_c[tid]);
  __syncthreads();
  if (lane==0){
    tlist[e1*NTOK + ls_b[e1] + s1] = tok*2;
    tlist[e2*NTOK + ls_b[e2] + s2] = tok*2 + 1;
  }
  if (tid<8)  atomicAdd(&psum[tid], ls_p[tid]);
  if (tid==8) atomicAdd(zsum, ls_z[0]);
}

// ---------------- weight |w| partial sums ----------------
__global__ void k_wabs(const float* __restrict__ w_in, const float* __restrict__ w_out,
                       float* __restrict__ part){
  int b = blockIdx.x, tid = threadIdx.x;
  const float* base = (b < 512) ? (w_in + (long)b*65536) : (w_out + (long)(b-512)*65536);
  const f32x4* p4 = (const f32x4*)base;
  float s = 0.f;
  for (int i = tid; i < 16384; i += 256){
    f32x4 v = p4[i];
    s += fabsf(v.x)+fabsf(v.y)+fabsf(v.z)+fabsf(v.w);
  }
  __shared__ float red[256];
  red[tid] = s; __syncthreads();
  for (int off=128; off; off>>=1){ if (tid<off) red[tid]+=red[tid+off]; __syncthreads(); }
  if (tid==0) part[b] = red[0];
}

__global__ void k_wmean(const float* __restrict__ part,
                        float* __restrict__ wrec_in, float* __restrict__ wrec_out,
                        float* __restrict__ wscl_in, float* __restrict__ wscl_out){
  int t = threadIdx.x;
  if (t < 8){
    float s = 0.f;
    for (int i=0;i<64;++i) s += part[t*64+i];
    float cmm = fmaxf(s/4194304.f, 1e-5f);
    wrec_in[t] = cmm; wscl_in[t] = 1.f/cmm;
  } else if (t < 16){
    int e = t-8; float s = 0.f;
    for (int i=0;i<32;++i) s += part[512 + e*32 + i];
    float cmm = fmaxf(s/2097152.f, 1e-5f);
    wrec_out[e] = cmm; wscl_out[e] = 1.f/cmm;
  }
}

// ---------------- ternarize + pack weights into MFMA fragment order ----------------
// chunk t (16B) within expert e: r = ((cb*KB + kb)*64 + lane); lane=lhi*16+l15
// holds W[cb*16 + l15][kb*64 + lhi*16 .. +16] -> coalesced 1KB wave loads in GEMM.
__global__ void k_packw(const float* __restrict__ w, i32x4* __restrict__ wq,
                        const float* __restrict__ wscl, int COLS, int K, int KB,
                        long chunksPerE){
  long t = (long)blockIdx.x*blockDim.x + threadIdx.x;
  int e = (int)(t / chunksPerE);
  long r = t - (long)e*chunksPerE;
  int lane = (int)(r & 63);
  long fb = r >> 6;
  int kb = (int)(fb % KB);
  int cb = (int)(fb / KB);
  int col = cb*16 + (lane & 15);
  int k0  = kb*64 + (lane >> 4)*16;
  const f32x4* src = (const f32x4*)(w + ((long)e*COLS + col)*K + k0);
  float s = wscl[e];
  f32x4 v0 = src[0], v1 = src[1], v2 = src[2], v3 = src[3];
  i32x4 o;
  o.x = (int)packq(v0, s, -1, 1);
  o.y = (int)packq(v1, s, -1, 1);
  o.z = (int)packq(v2, s, -1, 1);
  o.w = (int)packq(v3, s, -1, 1);
  wq[t] = o;
}

// ---------------- GEMM1: h = xq @ win^T, fused GLU, write glu + row absmax ----------------
__global__ __launch_bounds__(256) void k_gemm1(
    const signed char* __restrict__ xq, const signed char* __restrict__ wqin,
    const int* __restrict__ tlist, const int* __restrict__ cnts,
    const float* __restrict__ xrec, const float* __restrict__ wrec_in,
    float* __restrict__ glu, unsigned* __restrict__ habs)
{
  const int e = blockIdx.y;
  const int cnt = cnts[e];
  const int slot = blockIdx.x >> 5;
  const int row0 = slot << 7;
  if (row0 >= cnt) return;
  const int ctile = blockIdx.x & 31;              // glu cols [ctile*64, +64)
  const int wave = threadIdx.x >> 6, lane = threadIdx.x & 63;
  const int l15 = lane & 15, lhi = lane >> 4;
  const int rbase = row0 + wave*32;
  const int* tl = tlist + e*NTOK;

  const signed char* aptr[2];
  #pragma unroll
  for (int rt=0; rt<2; ++rt){
    int r = rbase + rt*16 + l15;
    int pr = tl[min(r, cnt-1)];
    aptr[rt] = xq + (long)(pr>>1)*DIMD + lhi*16;
  }
  // packed B bases (KB=16): frag (cb,kb) at byte ((cb*16+kb)*64+lane)*16
  const i32x4* bbase[8];
  {
    const signed char* wp = wqin + (long)e*4194304 + (long)lane*16;
    #pragma unroll
    for (int c=0;c<8;++c){
      int cb_c = (c<4) ? (ctile*4 + c) : (128 + ctile*4 + (c-4));
      bbase[c] = (const i32x4*)(wp + (long)cb_c*16384);
    }
  }
  i32x4 acc[2][8] = {};
  i32x4 ca0 = *(const i32x4*)(aptr[0]);
  i32x4 ca1 = *(const i32x4*)(aptr[1]);
  i32x4 cb[8];
  #pragma unroll
  for (int c=0;c<8;++c) cb[c] = bbase[c][0];
  #pragma unroll 1
  for (int kb=0; kb<15; ++kb){
    i32x4 na0 = *(const i32x4*)(aptr[0] + (kb+1)*64);
    i32x4 na1 = *(const i32x4*)(aptr[1] + (kb+1)*64);
    i32x4 nb[8];
    #pragma unroll
    for (int c=0;c<8;++c) nb[c] = bbase[c][(kb+1)*64];
    #pragma unroll
    for (int c=0;c<8;++c){
      acc[0][c] = __builtin_amdgcn_mfma_i32_16x16x64_i8(ca0, cb[c], acc[0][c], 0,0,0);
      acc[1][c] = __builtin_amdgcn_mfma_i32_16x16x64_i8(ca1, cb[c], acc[1][c], 0,0,0);
    }
    ca0 = na0; ca1 = na1;
    #pragma unroll
    for (int c=0;c<8;++c) cb[c] = nb[c];
  }
  #pragma unroll
  for (int c=0;c<8;++c){
    acc[0][c] = __builtin_amdgcn_mfma_i32_16x16x64_i8(ca0, cb[c], acc[0][c], 0,0,0);
    acc[1][c] = __builtin_amdgcn_mfma_i32_16x16x64_i8(ca1, cb[c], acc[1][c], 0,0,0);
  }
  const float wr = wrec_in[e];
  #pragma unroll
  for (int rt=0; rt<2; ++rt){
    #pragma unroll
    for (int i=0; i<4; ++i){
      int r = rbase + rt*16 + lhi*4 + i;
      bool valid = (r < cnt);
      int pr = valid ? tl[r] : 0;
      float dq = xrec[pr>>1] * wr;
      float m = 0.f;
      #pragma unroll
      for (int c=0;c<4;++c){
        float h1 = (float)acc[rt][c][i]   * dq;
        float gg = (float)acc[rt][c+4][i] * dq;
        float sil = h1 / (1.f + expf(-h1));
        float v = sil * gg;
        m = fmaxf(m, fabsf(v));
        if (valid) glu[(long)pr*HID + ctile*64 + c*16 + l15] = v;
      }
      #pragma unroll
      for (int mm=1; mm<16; mm<<=1) m = fmaxf(m, __shfl_xor(m, mm));
      if (valid && l15==0) atomicMax(habs + pr, __float_as_uint(m));
    }
  }
}

// ---------------- act_quant(glu) -> hq int8 ----------------
__global__ void k_quanth(const float* __restrict__ glu, const unsigned* __restrict__ habs,
                         signed char* __restrict__ hq, float* __restrict__ hrec){
  int p = blockIdx.x, t = threadIdx.x;
  float am = __uint_as_float(habs[p]);
  float cmm = fmaxf(am, 1e-5f);
  if (t==0) hrec[p] = cmm*(1.f/127.f);
  float s = 127.f/cmm;
  const f32x4* g4 = (const f32x4*)(glu + (long)p*HID);
  f32x4 v0 = g4[t*2], v1 = g4[t*2+1];
  uint2 u; u.x = packq(v0, s, -128, 127); u.y = packq(v1, s, -128, 127);
  ((uint2*)(hq + (long)p*HID))[t] = u;
}

// ---------------- GEMM2: pout[pr] = gate * hrec * wrec * (hq @ wout^T) ----------------
__global__ __launch_bounds__(256) void k_gemm2(
    const signed char* __restrict__ hq, const signed char* __restrict__ wqout,
    const int* __restrict__ tlist, const int* __restrict__ cnts,
    const float* __restrict__ hrec, const float* __restrict__ gatep,
    const float* __restrict__ wrec_out, float* __restrict__ pout)
{
  const int e = blockIdx.y;
  const int cnt = cnts[e];
  const int slot = blockIdx.x >> 3;
  const int row0 = slot << 7;
  if (row0 >= cnt) return;
  const int ctile = blockIdx.x & 7;
  const int dcol0 = ctile*128;
  const int wave = threadIdx.x >> 6, lane = threadIdx.x & 63;
  const int l15 = lane & 15, lhi = lane >> 4;
  const int rbase = row0 + wave*32;
  const int* tl = tlist + e*NTOK;

  const signed char* aptr[2];
  #pragma unroll
  for (int rt=0; rt<2; ++rt){
    int r = rbase + rt*16 + l15;
    int pr = tl[min(r, cnt-1)];
    aptr[rt] = hq + (long)pr*HID + lhi*16;
  }
  // packed B bases (KB=32): frag (cb,kb) at byte ((cb*32+kb)*64+lane)*16
  const i32x4* bbase[8];
  {
    const signed char* wp = wqout + (long)e*2097152 + (long)lane*16;
    #pragma unroll
    for (int c=0;c<8;++c){
      int cb_c = ctile*8 + c;
      bbase[c] = (const i32x4*)(wp + (long)cb_c*32768);
    }
  }
  i32x4 acc[2][8] = {};
  i32x4 ca0 = *(const i32x4*)(aptr[0]);
  i32x4 ca1 = *(const i32x4*)(aptr[1]);
  i32x4 cb[8];
  #pragma unroll
  for (int c=0;c<8;++c) cb[c] = bbase[c][0];
  #pragma unroll 1
  for (int kb=0; kb<31; ++kb){
    i32x4 na0 = *(const i32x4*)(aptr[0] + (kb+1)*64);
    i32x4 na1 = *(const i32x4*)(aptr[1] + (kb+1)*64);
    i32x4 nb[8];
    #pragma unroll
    for (int c=0;c<8;++c) nb[c] = bbase[c][(kb+1)*64];
    #pragma unroll
    for (int c=0;c<8;++c){
      acc[0][c] = __builtin_amdgcn_mfma_i32_16x16x64_i8(ca0, cb[c], acc[0][c], 0,0,0);
      acc[1][c] = __builtin_amdgcn_mfma_i32_16x16x64_i8(ca1, cb[c], acc[1][c], 0,0,0);
    }
    ca0 = na0; ca1 = na1;
    #pragma unroll
    for (int c=0;c<8;++c) cb[c] = nb[c];
  }
  #pragma unroll
  for (int c=0;c<8;++c){
    acc[0][c] = __builtin_amdgcn_mfma_i32_16x16x64_i8(ca0, cb[c], acc[0][c], 0,0,0);
    acc[1][c] = __builtin_amdgcn_mfma_i32_16x16x64_i8(ca1, cb[c], acc[1][c], 0,0,0);
  }
  const float wr = wrec_out[e];
  #pragma unroll
  for (int rt=0; rt<2; ++rt){
    #pragma unroll
    for (int i=0; i<4; ++i){
      int r = rbase + rt*16 + lhi*4 + i;
      if (r >= cnt) continue;
      int pr = tl[r];
      float f = gatep[pr] * hrec[pr] * wr;
      #pragma unroll
      for (int c=0;c<8;++c)
        pout[(long)pr*DIMD + dcol0 + c*16 + l15] = (float)acc[rt][c][i] * f;
    }
  }
}

// ---------------- combine: y = bias + pout[2t] + pout[2t+1] ----------------
__global__ void k_combine(const float* __restrict__ pout, const float* __restrict__ bias,
                          float* __restrict__ y){
  long idx = (long)blockIdx.x*blockDim.x + threadIdx.x;   // over NTOK*DIMD/4
  int tok = (int)(idx >> 8);
  int c4  = (int)(idx & 255);
  f32x4 b  = ((const f32x4*)bias)[c4];
  const f32x4* p = (const f32x4*)(pout + (long)tok*2*DIMD);
  f32x4 r = b + p[c4] + p[256 + c4];
  ((f32x4*)(y + (long)tok*DIMD))[c4] = r;
}

// ---------------- loss ----------------
__global__ void k_loss(const int* __restrict__ cnts, const float* __restrict__ psum,
                       const float* __restrict__ zsum, float* __restrict__ out){
  if (threadIdx.x==0 && blockIdx.x==0){
    float sp=0.f, sf=0.f, sw=0.f;
    for (int e=0;e<8;++e){
      float f = (float)cnts[e];
      sp += psum[e]; sf += f; sw += psum[e]*f;
    }
    float loss = 8.f*sw/(sp*sf) + 0.1f*zsum[0]/(float)NTOK;
    out[(long)NTOK*DIMD] = loss;
  }
}

extern "C" void kernel_launch(void* const* d_in, const int* in_sizes, int n_in,
                              void* d_out, int out_size, void* d_ws, size_t ws_size,
                              hipStream_t stream){
  const float* x     = (const float*)d_in[0];
  const float* wg    = (const float*)d_in[1];
  const float* w_in  = (const float*)d_in[2];
  const float* w_out = (const float*)d_in[3];
  const float* bias  = (const float*)d_in[4];
  float* y = (float*)d_out;
  char* ws = (char*)d_ws;

  signed char* xq    = (signed char*)(ws + XQ_OFF);
  signed char* wqin  = (signed char*)(ws + WQIN_OFF);
  signed char* wqout = (signed char*)(ws + WQOUT_OFF);
  signed char* hq    = (signed char*)(ws + HQ_OFF);
  float* glu   = (float*)(ws + GLU_OFF);
  float* pout  = (float*)(ws + GLU_OFF);   // reuse: glu dead after k_quanth
  float* xrec  = (float*)(ws + XREC_OFF);
  float* gatep = (float*)(ws + GATE_OFF);
  float* hrec  = (float*)(ws + HREC_OFF);
  unsigned* habs = (unsigned*)(ws + HABS_OFF);
  int* tlist = (int*)(ws + TLIST_OFF);
  int* cnts  = (int*)(ws + CNT_OFF);
  float* psum = (float*)(ws + PSUM_OFF);
  float* zsum = (float*)(ws + ZSUM_OFF);
  float* part = (float*)(ws + PART_OFF);
  float* wrec_in  = (float*)(ws + WRECIN_OFF);
  float* wrec_out = (float*)(ws + WRECOUT_OFF);
  float* wscl_in  = (float*)(ws + WSCLIN_OFF);
  float* wscl_out = (float*)(ws + WSCLOUT_OFF);

  k_init  <<<64, 256, 0, stream>>>(habs, cnts, psum, zsum);
  k_router<<<512, 1024, 0, stream>>>(x, wg, xq, xrec, gatep, tlist, cnts, psum, zsum);
  k_wabs  <<<768, 256, 0, stream>>>(w_in, w_out, part);
  k_wmean <<<1, 64, 0, stream>>>(part, wrec_in, wrec_out, wscl_in, wscl_out);
  // pack: w_in  COLS=4096 K=1024 KB=16, chunks/e = 262144  -> 2M threads
  k_packw <<<8192, 256, 0, stream>>>(w_in,  (i32x4*)wqin,  wscl_in,  4096, 1024, 16, 262144L);
  // pack: w_out COLS=1024 K=2048 KB=32, chunks/e = 131072  -> 1M threads
  k_packw <<<4096, 256, 0, stream>>>(w_out, (i32x4*)wqout, wscl_out, 1024, 2048, 32, 131072L);
  k_gemm1 <<<dim3(2048, 8), 256, 0, stream>>>(xq, wqin, tlist, cnts, xrec, wrec_in, glu, habs);
  k_quanth<<<NPAIR, 256, 0, stream>>>(glu, habs, hq, hrec);
  k_gemm2 <<<dim3(512, 8), 256, 0, stream>>>(hq, wqout, tlist, cnts, hrec, gatep, wrec_out, pout);
  k_combine<<<8192, 256, 0, stream>>>(pout, bias, y);
  k_loss  <<<1, 64, 0, stream>>>(cnts, psum, zsum, y);
}

// Round 3
// 479.168 us; speedup vs baseline: 1.7570x; 1.0363x over previous
//
#include <hip/hip_runtime.h>
#include <math.h>

typedef __attribute__((ext_vector_type(4))) int   i32x4;
typedef __attribute__((ext_vector_type(4))) float f32x4;
typedef __attribute__((ext_vector_type(8))) unsigned short u16x8;

#define NTOK   8192
#define DIMD   1024
#define HID    2048
#define NEXP   8
#define NPAIR  16384

// ---- workspace byte offsets ----
#define XQ_OFF      0L           // int8 [8192][1024]
#define WQIN_OFF    8388608L     // int8 packed frags [8][256 cb][16 kb][64 lane][16]
#define WQOUT_OFF   41943040L    // int8 packed frags [8][64 cb][32 kb][64 lane][16]
#define HQ_OFF      58720256L    // int8 [16384][2048]
#define GLU_OFF     92274688L    // bf16 [16384][2048] ; later reused as pout f32 [16384][1024]
#define XREC_OFF    226492416L   // f32 [8192]
#define GATE_OFF    226525184L   // f32 [16384]
#define HREC_OFF    226590720L   // f32 [16384]
#define HABS_OFF    226656256L   // u32 [16384]
#define TLIST_OFF   226721792L   // int [8][8192]
#define CNT_OFF     226983936L   // int [8]
#define PSUM_OFF    226983968L   // f32 [8]
#define ZSUM_OFF    226984000L   // f32 [1]
#define PART_OFF    226984032L   // f32 [768]
#define WRECIN_OFF  226988128L
#define WRECOUT_OFF 226988160L
#define WSCLIN_OFF  226988192L
#define WSCLOUT_OFF 226988224L

__device__ __forceinline__ int clampi(int v, int lo, int hi){ return v<lo?lo:(v>hi?hi:v); }

__device__ __forceinline__ unsigned packq(f32x4 v, float s, int lo, int hi){
  int q0 = clampi((int)rintf(v.x*s), lo, hi);
  int q1 = clampi((int)rintf(v.y*s), lo, hi);
  int q2 = clampi((int)rintf(v.z*s), lo, hi);
  int q3 = clampi((int)rintf(v.w*s), lo, hi);
  return (unsigned)((q0&255)|((q1&255)<<8)|((q2&255)<<16)|((q3&255)<<24));
}

__device__ __forceinline__ unsigned short f2bf(float f){
  unsigned u = __float_as_uint(f);
  u += 0x7fffu + ((u >> 16) & 1u);
  return (unsigned short)(u >> 16);
}
__device__ __forceinline__ float bf2f(unsigned short b){
  return __uint_as_float(((unsigned)b) << 16);
}

// ---------------- init: zero accumulators ----------------
__global__ void k_init(unsigned* __restrict__ habs, int* __restrict__ cnts,
                       float* __restrict__ psum, float* __restrict__ zsum){
  int i = blockIdx.x*blockDim.x + threadIdx.x;
  if (i < NPAIR) habs[i] = 0u;
  if (i < 8){ cnts[i]=0; psum[i]=0.f; }
  if (i == 8) zsum[0]=0.f;
}

// ---------------- router + act_quant(x) ----------------
__global__ __launch_bounds__(1024) void k_router(
    const float* __restrict__ x, const float* __restrict__ wg,
    signed char* __restrict__ xq, float* __restrict__ xrec,
    float* __restrict__ gatep, int* __restrict__ tlist, int* __restrict__ cnts,
    float* __restrict__ psum, float* __restrict__ zsum)
{
  __shared__ float ls_p[8]; __shared__ float ls_z[1];
  __shared__ int ls_c[8];  __shared__ int ls_b[8];
  int tid = threadIdx.x;
  if (tid<8){ ls_p[tid]=0.f; ls_c[tid]=0; }
  if (tid==8) ls_z[0]=0.f;
  __syncthreads();
  int wave = tid>>6, lane = tid&63;
  int tok = blockIdx.x*16 + wave;

  const f32x4* x4 = (const f32x4*)(x + (long)tok*DIMD) + lane*4;
  f32x4 xv[4];
  #pragma unroll
  for (int j=0;j<4;++j) xv[j] = x4[j];

  float amax = 0.f;
  float lg[8] = {0,0,0,0,0,0,0,0};
  const f32x4* wg4 = (const f32x4*)wg;
  #pragma unroll
  for (int j=0;j<16;++j){
    float xd = xv[j>>2][j&3];
    amax = fmaxf(amax, fabsf(xd));
    int d = lane*16 + j;
    f32x4 w0 = wg4[d*2], w1 = wg4[d*2+1];
    lg[0]+=xd*w0.x; lg[1]+=xd*w0.y; lg[2]+=xd*w0.z; lg[3]+=xd*w0.w;
    lg[4]+=xd*w1.x; lg[5]+=xd*w1.y; lg[6]+=xd*w1.z; lg[7]+=xd*w1.w;
  }
  for (int m=1;m<64;m<<=1){
    amax = fmaxf(amax, __shfl_xor(amax, m));
    #pragma unroll
    for (int e=0;e<8;++e) lg[e] += __shfl_xor(lg[e], m);
  }
  float cm = fmaxf(amax, 1e-5f);
  float sx = 127.f/cm;
  unsigned p0 = packq(xv[0], sx, -128, 127);
  unsigned p1 = packq(xv[1], sx, -128, 127);
  unsigned p2 = packq(xv[2], sx, -128, 127);
  unsigned p3 = packq(xv[3], sx, -128, 127);
  i32x4 pk; pk.x=(int)p0; pk.y=(int)p1; pk.z=(int)p2; pk.w=(int)p3;
  *(i32x4*)(xq + (long)tok*DIMD + lane*16) = pk;

  int e1=0, e2=0, s1=0, s2=0;
  if (lane==0){
    xrec[tok] = cm*(1.f/127.f);
    e1 = 0;
    for (int e=1;e<8;++e) if (lg[e] > lg[e1]) e1 = e;
    e2 = (e1==0)?1:0;
    for (int e=0;e<8;++e) if (e!=e1 && lg[e] > lg[e2]) e2 = e;
    float t = expf(lg[e2]-lg[e1]);
    gatep[tok*2]   = 1.f/(1.f+t);
    gatep[tok*2+1] = t/(1.f+t);
    float mx = lg[e1], sum = 0.f, pr[8];
    #pragma unroll
    for (int e=0;e<8;++e){ pr[e] = expf(lg[e]-mx); sum += pr[e]; }
    float inv = 1.f/sum;
    #pragma unroll
    for (int e=0;e<8;++e) atomicAdd(&ls_p[e], pr[e]*inv);
    float lse = mx + logf(sum);
    atomicAdd(&ls_z[0], lse*lse);
    s1 = atomicAdd(&ls_c[e1], 1);
    s2 = atomicAdd(&ls_c[e2], 1);
  }
  __syncthreads();
  if (tid<8) ls_b[tid] = atomicAdd(&cnts[tid], ls_c[tid]);
  __syncthreads();
  if (lane==0){
    tlist[e1*NTOK + ls_b[e1] + s1] = tok*2;
    tlist[e2*NTOK + ls_b[e2] + s2] = tok*2 + 1;
  }
  if (tid<8)  atomicAdd(&psum[tid], ls_p[tid]);
  if (tid==8) atomicAdd(zsum, ls_z[0]);
}

// ---------------- weight |w| partial sums ----------------
__global__ void k_wabs(const float* __restrict__ w_in, const float* __restrict__ w_out,
                       float* __restrict__ part){
  int b = blockIdx.x, tid = threadIdx.x;
  const float* base = (b < 512) ? (w_in + (long)b*65536) : (w_out + (long)(b-512)*65536);
  const f32x4* p4 = (const f32x4*)base;
  float s = 0.f;
  for (int i = tid; i < 16384; i += 256){
    f32x4 v = p4[i];
    s += fabsf(v.x)+fabsf(v.y)+fabsf(v.z)+fabsf(v.w);
  }
  __shared__ float red[256];
  red[tid] = s; __syncthreads();
  for (int off=128; off; off>>=1){ if (tid<off) red[tid]+=red[tid+off]; __syncthreads(); }
  if (tid==0) part[b] = red[0];
}

__global__ void k_wmean(const float* __restrict__ part,
                        float* __restrict__ wrec_in, float* __restrict__ wrec_out,
                        float* __restrict__ wscl_in, float* __restrict__ wscl_out){
  int t = threadIdx.x;
  if (t < 8){
    float s = 0.f;
    for (int i=0;i<64;++i) s += part[t*64+i];
    float cmm = fmaxf(s/4194304.f, 1e-5f);
    wrec_in[t] = cmm; wscl_in[t] = 1.f/cmm;
  } else if (t < 16){
    int e = t-8; float s = 0.f;
    for (int i=0;i<32;++i) s += part[512 + e*32 + i];
    float cmm = fmaxf(s/2097152.f, 1e-5f);
    wrec_out[e] = cmm; wscl_out[e] = 1.f/cmm;
  }
}

// ---------------- ternarize + pack weights into MFMA fragment order ----------------
__global__ void k_packw(const float* __restrict__ w, i32x4* __restrict__ wq,
                        const float* __restrict__ wscl, int COLS, int K, int KB,
                        long chunksPerE){
  long t = (long)blockIdx.x*blockDim.x + threadIdx.x;
  int e = (int)(t / chunksPerE);
  long r = t - (long)e*chunksPerE;
  int lane = (int)(r & 63);
  long fb = r >> 6;
  int kb = (int)(fb % KB);
  int cb = (int)(fb / KB);
  int col = cb*16 + (lane & 15);
  int k0  = kb*64 + (lane >> 4)*16;
  const f32x4* src = (const f32x4*)(w + ((long)e*COLS + col)*K + k0);
  float s = wscl[e];
  f32x4 v0 = src[0], v1 = src[1], v2 = src[2], v3 = src[3];
  i32x4 o;
  o.x = (int)packq(v0, s, -1, 1);
  o.y = (int)packq(v1, s, -1, 1);
  o.z = (int)packq(v2, s, -1, 1);
  o.w = (int)packq(v3, s, -1, 1);
  wq[t] = o;
}

#define MFMA8(A, B, ACC) \
  { _Pragma("unroll") for (int c=0;c<8;++c) \
      ACC[c] = __builtin_amdgcn_mfma_i32_16x16x64_i8(A, B[c], ACC[c], 0,0,0); }

// ---------------- GEMM1: h = xq @ win^T, fused GLU, write glu(bf16) + row absmax ----------------
__global__ __launch_bounds__(256) void k_gemm1(
    const signed char* __restrict__ xq, const signed char* __restrict__ wqin,
    const int* __restrict__ tlist, const int* __restrict__ cnts,
    const float* __restrict__ xrec, const float* __restrict__ wrec_in,
    unsigned short* __restrict__ glu, unsigned* __restrict__ habs)
{
  const int e = blockIdx.y;
  const int cnt = cnts[e];
  const int slot = blockIdx.x >> 5;
  const int row0 = slot << 7;
  if (row0 >= cnt) return;
  const int ctile = blockIdx.x & 31;              // glu cols [ctile*64, +64)
  const int wave = threadIdx.x >> 6, lane = threadIdx.x & 63;
  const int l15 = lane & 15, lhi = lane >> 4;
  const int rbase = row0 + wave*32;
  const int* tl = tlist + e*NTOK;

  const i32x4* aptr[2];
  #pragma unroll
  for (int rt=0; rt<2; ++rt){
    int r = rbase + rt*16 + l15;
    int pr = tl[min(r, cnt-1)];
    aptr[rt] = (const i32x4*)(xq + (long)(pr>>1)*DIMD + lhi*16);
  }
  const i32x4* bbase[8];
  {
    const signed char* wp = wqin + (long)e*4194304 + (long)lane*16;
    #pragma unroll
    for (int c=0;c<8;++c){
      int cb_c = (c<4) ? (ctile*4 + c) : (128 + ctile*4 + (c-4));
      bbase[c] = (const i32x4*)(wp + (long)cb_c*16384);
    }
  }
  i32x4 acc0[8] = {}, acc1[8] = {};
  i32x4 e_a0 = aptr[0][0],  e_a1 = aptr[1][0];
  i32x4 o_a0 = aptr[0][4],  o_a1 = aptr[1][4];
  i32x4 e_b[8], o_b[8];
  #pragma unroll
  for (int c=0;c<8;++c){ e_b[c] = bbase[c][0]; o_b[c] = bbase[c][64]; }
  #pragma unroll 1
  for (int kb=0; kb<14; kb+=2){
    MFMA8(e_a0, e_b, acc0); MFMA8(e_a1, e_b, acc1);
    e_a0 = aptr[0][(kb+2)*4]; e_a1 = aptr[1][(kb+2)*4];
    #pragma unroll
    for (int c=0;c<8;++c) e_b[c] = bbase[c][(kb+2)*64];
    MFMA8(o_a0, o_b, acc0); MFMA8(o_a1, o_b, acc1);
    o_a0 = aptr[0][(kb+3)*4]; o_a1 = aptr[1][(kb+3)*4];
    #pragma unroll
    for (int c=0;c<8;++c) o_b[c] = bbase[c][(kb+3)*64];
  }
  MFMA8(e_a0, e_b, acc0); MFMA8(e_a1, e_b, acc1);
  MFMA8(o_a0, o_b, acc0); MFMA8(o_a1, o_b, acc1);

  const float wr = wrec_in[e];
  #pragma unroll
  for (int rt=0; rt<2; ++rt){
    #pragma unroll
    for (int i=0; i<4; ++i){
      int r = rbase + rt*16 + lhi*4 + i;
      bool valid = (r < cnt);
      int pr = valid ? tl[r] : 0;
      float dq = xrec[pr>>1] * wr;
      float m = 0.f;
      #pragma unroll
      for (int c=0;c<4;++c){
        float h1 = (float)(rt==0 ? acc0[c][i]   : acc1[c][i])   * dq;
        float gg = (float)(rt==0 ? acc0[c+4][i] : acc1[c+4][i]) * dq;
        float sil = h1 / (1.f + expf(-h1));
        float v = sil * gg;
        m = fmaxf(m, fabsf(v));
        if (valid) glu[(long)pr*HID + ctile*64 + c*16 + l15] = f2bf(v);
      }
      #pragma unroll
      for (int mm=1; mm<16; mm<<=1) m = fmaxf(m, __shfl_xor(m, mm));
      if (valid && l15==0) atomicMax(habs + pr, __float_as_uint(m));
    }
  }
}

// ---------------- act_quant(glu bf16) -> hq int8 ----------------
__global__ void k_quanth(const unsigned short* __restrict__ glu, const unsigned* __restrict__ habs,
                         signed char* __restrict__ hq, float* __restrict__ hrec){
  int p = blockIdx.x, t = threadIdx.x;
  float am = __uint_as_float(habs[p]);
  float cmm = fmaxf(am, 1e-5f);
  if (t==0) hrec[p] = cmm*(1.f/127.f);
  float s = 127.f/cmm;
  u16x8 v = ((const u16x8*)(glu + (long)p*HID))[t];
  f32x4 f0, f1;
  f0.x=bf2f(v[0]); f0.y=bf2f(v[1]); f0.z=bf2f(v[2]); f0.w=bf2f(v[3]);
  f1.x=bf2f(v[4]); f1.y=bf2f(v[5]); f1.z=bf2f(v[6]); f1.w=bf2f(v[7]);
  uint2 u; u.x = packq(f0, s, -128, 127); u.y = packq(f1, s, -128, 127);
  ((uint2*)(hq + (long)p*HID))[t] = u;
}

// ---------------- GEMM2: pout[pr] = gate * hrec * wrec * (hq @ wout^T) ----------------
__global__ __launch_bounds__(256) void k_gemm2(
    const signed char* __restrict__ hq, const signed char* __restrict__ wqout,
    const int* __restrict__ tlist, const int* __restrict__ cnts,
    const float* __restrict__ hrec, const float* __restrict__ gatep,
    const float* __restrict__ wrec_out, float* __restrict__ pout)
{
  const int e = blockIdx.y;
  const int cnt = cnts[e];
  const int slot = blockIdx.x >> 3;
  const int row0 = slot << 7;
  if (row0 >= cnt) return;
  const int ctile = blockIdx.x & 7;
  const int dcol0 = ctile*128;
  const int wave = threadIdx.x >> 6, lane = threadIdx.x & 63;
  const int l15 = lane & 15, lhi = lane >> 4;
  const int rbase = row0 + wave*32;
  const int* tl = tlist + e*NTOK;

  const i32x4* aptr[2];
  #pragma unroll
  for (int rt=0; rt<2; ++rt){
    int r = rbase + rt*16 + l15;
    int pr = tl[min(r, cnt-1)];
    aptr[rt] = (const i32x4*)(hq + (long)pr*HID + lhi*16);
  }
  const i32x4* bbase[8];
  {
    const signed char* wp = wqout + (long)e*2097152 + (long)lane*16;
    #pragma unroll
    for (int c=0;c<8;++c){
      int cb_c = ctile*8 + c;
      bbase[c] = (const i32x4*)(wp + (long)cb_c*32768);
    }
  }
  i32x4 acc0[8] = {}, acc1[8] = {};
  i32x4 e_a0 = aptr[0][0],  e_a1 = aptr[1][0];
  i32x4 o_a0 = aptr[0][4],  o_a1 = aptr[1][4];
  i32x4 e_b[8], o_b[8];
  #pragma unroll
  for (int c=0;c<8;++c){ e_b[c] = bbase[c][0]; o_b[c] = bbase[c][64]; }
  #pragma unroll 1
  for (int kb=0; kb<30; kb+=2){
    MFMA8(e_a0, e_b, acc0); MFMA8(e_a1, e_b, acc1);
    e_a0 = aptr[0][(kb+2)*4]; e_a1 = aptr[1][(kb+2)*4];
    #pragma unroll
    for (int c=0;c<8;++c) e_b[c] = bbase[c][(kb+2)*64];
    MFMA8(o_a0, o_b, acc0); MFMA8(o_a1, o_b, acc1);
    o_a0 = aptr[0][(kb+3)*4]; o_a1 = aptr[1][(kb+3)*4];
    #pragma unroll
    for (int c=0;c<8;++c) o_b[c] = bbase[c][(kb+3)*64];
  }
  MFMA8(e_a0, e_b, acc0); MFMA8(e_a1, e_b, acc1);
  MFMA8(o_a0, o_b, acc0); MFMA8(o_a1, o_b, acc1);

  const float wr = wrec_out[e];
  #pragma unroll
  for (int rt=0; rt<2; ++rt){
    #pragma unroll
    for (int i=0; i<4; ++i){
      int r = rbase + rt*16 + lhi*4 + i;
      if (r >= cnt) continue;
      int pr = tl[r];
      float f = gatep[pr] * hrec[pr] * wr;
      #pragma unroll
      for (int c=0;c<8;++c)
        pout[(long)pr*DIMD + dcol0 + c*16 + l15] = (float)(rt==0 ? acc0[c][i] : acc1[c][i]) * f;
    }
  }
}

// ---------------- combine: y = bias + pout[2t] + pout[2t+1] ----------------
__global__ void k_combine(const float* __restrict__ pout, const float* __restrict__ bias,
                          float* __restrict__ y){
  long idx = (long)blockIdx.x*blockDim.x + threadIdx.x;
  int tok = (int)(idx >> 8);
  int c4  = (int)(idx & 255);
  f32x4 b  = ((const f32x4*)bias)[c4];
  const f32x4* p = (const f32x4*)(pout + (long)tok*2*DIMD);
  f32x4 r = b + p[c4] + p[256 + c4];
  ((f32x4*)(y + (long)tok*DIMD))[c4] = r;
}

// ---------------- loss ----------------
__global__ void k_loss(const int* __restrict__ cnts, const float* __restrict__ psum,
                       const float* __restrict__ zsum, float* __restrict__ out){
  if (threadIdx.x==0 && blockIdx.x==0){
    float sp=0.f, sf=0.f, sw=0.f;
    for (int e=0;e<8;++e){
      float f = (float)cnts[e];
      sp += psum[e]; sf += f; sw += psum[e]*f;
    }
    float loss = 8.f*sw/(sp*sf) + 0.1f*zsum[0]/(float)NTOK;
    out[(long)NTOK*DIMD] = loss;
  }
}

extern "C" void kernel_launch(void* const* d_in, const int* in_sizes, int n_in,
                              void* d_out, int out_size, void* d_ws, size_t ws_size,
                              hipStream_t stream){
  const float* x     = (const float*)d_in[0];
  const float* wg    = (const float*)d_in[1];
  const float* w_in  = (const float*)d_in[2];
  const float* w_out = (const float*)d_in[3];
  const float* bias  = (const float*)d_in[4];
  float* y = (float*)d_out;
  char* ws = (char*)d_ws;

  signed char* xq    = (signed char*)(ws + XQ_OFF);
  signed char* wqin  = (signed char*)(ws + WQIN_OFF);
  signed char* wqout = (signed char*)(ws + WQOUT_OFF);
  signed char* hq    = (signed char*)(ws + HQ_OFF);
  unsigned short* glu = (unsigned short*)(ws + GLU_OFF);
  float* pout  = (float*)(ws + GLU_OFF);
  float* xrec  = (float*)(ws + XREC_OFF);
  float* gatep = (float*)(ws + GATE_OFF);
  float* hrec  = (float*)(ws + HREC_OFF);
  unsigned* habs = (unsigned*)(ws + HABS_OFF);
  int* tlist = (int*)(ws + TLIST_OFF);
  int* cnts  = (int*)(ws + CNT_OFF);
  float* psum = (float*)(ws + PSUM_OFF);
  float* zsum = (float*)(ws + ZSUM_OFF);
  float* part = (float*)(ws + PART_OFF);
  float* wrec_in  = (float*)(ws + WRECIN_OFF);
  float* wrec_out = (float*)(ws + WRECOUT_OFF);
  float* wscl_in  = (float*)(ws + WSCLIN_OFF);
  float* wscl_out = (float*)(ws + WSCLOUT_OFF);

  k_init  <<<64, 256, 0, stream>>>(habs, cnts, psum, zsum);
  k_router<<<512, 1024, 0, stream>>>(x, wg, xq, xrec, gatep, tlist, cnts, psum, zsum);
  k_wabs  <<<768, 256, 0, stream>>>(w_in, w_out, part);
  k_wmean <<<1, 64, 0, stream>>>(part, wrec_in, wrec_out, wscl_in, wscl_out);
  k_packw <<<8192, 256, 0, stream>>>(w_in,  (i32x4*)wqin,  wscl_in,  4096, 1024, 16, 262144L);
  k_packw <<<4096, 256, 0, stream>>>(w_out, (i32x4*)wqout, wscl_out, 1024, 2048, 32, 131072L);
  k_gemm1 <<<dim3(2048, 8), 256, 0, stream>>>(xq, wqin, tlist, cnts, xrec, wrec_in, glu, habs);
  k_quanth<<<NPAIR, 256, 0, stream>>>(glu, habs, hq, hrec);
  k_gemm2 <<<dim3(512, 8), 256, 0, stream>>>(hq, wqout, tlist, cnts, hrec, gatep, wrec_out, pout);
  k_combine<<<8192, 256, 0, stream>>>(pout, bias, y);
  k_loss  <<<1, 64, 0, stream>>>(cnts, psum, zsum, y);
}